// Round 17
// baseline (150.495 us; speedup 1.0000x reference)
//
#include <hip/hip_runtime.h>

// ---- problem constants ----
#define CC   192                 // C
#define C3   576                 // 3C
#define HH   64
#define WW   64
#define HWP  4096                // H*W
#define BB   8
#define DH   48                  // C/HEADS
#define QKV_B (C3*HWP)           // elements per batch of conv-out tensor
#define X_B   (CC*HWP)
#define OUT_HALF ((size_t)BB*X_B)

typedef short bf16x8 __attribute__((ext_vector_type(8)));
typedef float f32x4  __attribute__((ext_vector_type(4)));

#define AS1(p) ((__attribute__((address_space(1))) void*)(p))
#define AS3(p) ((__attribute__((address_space(3))) void*)(p))

__device__ __forceinline__ ushort f2bf(float v) {
    union { float f; unsigned u; } a; a.f = v;
    unsigned r = a.u + 0x7FFF + ((a.u >> 16) & 1);   // RNE
    return (ushort)(r >> 16);
}
__device__ __forceinline__ float bf2f(ushort h) {
    union { float f; unsigned u; } a; a.u = ((unsigned)h) << 16; return a.f;
}

// ============================================================
// {x,y} (b,192,4096) fp32 -> XT (tsr,b,4096,192) bf16 single. z in [0,16).
// ============================================================
__global__ __launch_bounds__(256) void convert_single_kernel(const float* __restrict__ x,
    const float* __restrict__ y, ushort* __restrict__ xt)
{
    __shared__ float L[64][65];
    const int n0 = blockIdx.x * 64, c0 = blockIdx.y * 64, z = blockIdx.z;
    const int t = threadIdx.x;
    const float* ip = ((z < 8) ? x : y) + (size_t)(z & 7) * X_B;
    #pragma unroll
    for (int i = 0; i < 16; i++) {
        int e = t + 256 * i;
        int r = e >> 6, col = e & 63;
        L[r][col] = ip[(size_t)(c0 + r) * HWP + n0 + col];
    }
    __syncthreads();
    #pragma unroll
    for (int i = 0; i < 4; i++) {
        int e = t + 256 * i;
        int n = e >> 4, c4 = e & 15;
        ushort hi[4];
        #pragma unroll
        for (int j = 0; j < 4; j++)
            hi[j] = f2bf(L[c4 * 4 + j][n]);
        size_t base = ((size_t)z * HWP + n0 + n) * 192 + c0 + c4 * 4;
        *(ushort4*)&xt[base] = make_ushort4(hi[0], hi[1], hi[2], hi[3]);
    }
}

// ============================================================
// v bf16 (16 batch-slices,192,4096) -> VT (...,4096,192) transpose. z in [0,16).
// ============================================================
__global__ __launch_bounds__(256) void vtrans_kernel(const ushort* __restrict__ in,
    ushort* __restrict__ vt)
{
    __shared__ __align__(16) ushort L[64][72];
    const int n0 = blockIdx.x * 64, c0 = blockIdx.y * 64, z = blockIdx.z;
    const int t = threadIdx.x;
    const ushort* ip = in + (size_t)z * X_B;
    #pragma unroll
    for (int i = 0; i < 2; i++) {
        int e = t + 256 * i;            // 512 units of 8 ushorts
        int r = e >> 3, u8 = e & 7;
        *(bf16x8*)&L[r][u8 * 8] = *(const bf16x8*)&ip[(size_t)(c0 + r) * HWP + n0 + u8 * 8];
    }
    __syncthreads();
    #pragma unroll
    for (int i = 0; i < 4; i++) {
        int e = t + 256 * i;            // 1024: 64 n x 16 c4
        int n = e >> 4, c4 = e & 15;
        ushort o[4];
        #pragma unroll
        for (int j = 0; j < 4; j++) o[j] = L[c4 * 4 + j][n];
        *(ushort4*)&vt[((size_t)z * HWP + n0 + n) * 192 + c0 + c4 * 4] =
            make_ushort4(o[0], o[1], o[2], o[3]);
    }
}

// ============================================================
// w_qkv -> Wc(640,192) bf16 SINGLE, zero-padded rows 576..639
// ============================================================
__global__ __launch_bounds__(256) void wconvert_kernel(const float* __restrict__ wq,
    ushort* __restrict__ wc)
{
    int e = (blockIdx.x * 256 + threadIdx.x) * 4;    // 640*192 total
    int oc = e / 192, k = e % 192;
    ushort o[4] = {0, 0, 0, 0};
    if (oc < C3) {
        #pragma unroll
        for (int j = 0; j < 4; j++)
            o[j] = f2bf(wq[oc * CC + k + j]);
    }
    *(ushort4*)&wc[e] = make_ushort4(o[0], o[1], o[2], o[3]);
}

// ============================================================
// conv1x1 via MFMA, X-resident + W-IN-REGISTERS: X (96 KB) staged once;
// per mi, each wave preloads its 24 W fragments (16B global loads, L2-hot)
// into VGPRs -> the 6-chunk MFMA loop has ZERO barriers (LDS X reads +
// register W only; compiler free-schedules waits). Barriers remain only in
// the proven E epilogue. Grid 256 x 512 thr, LDS 128 KB.
// ============================================================
__global__ __launch_bounds__(512) void conv1x1_mfma(const ushort* __restrict__ XT,
    const ushort* __restrict__ Wc, ushort* __restrict__ t1s)
{
    __shared__ __align__(16) ushort Xres[6][1024 * 8];  // 6 x 16 KB resident
    __shared__ __align__(16) ushort E[128][128];        // 32 KB epilogue
    const int t = threadIdx.x;
    const int lane = t & 63, w = t >> 6;
    const int wm = w >> 2, wn = w & 3;
    const int fr = lane & 15, kg = lane >> 4;
    const int g = blockIdx.x;
    const int bg = g & 7, s = g >> 3;           // s in [0,32)
    const int tsr = s >> 4;
    const int nt = s & 15;
    const int n0 = nt * 256;
    const ushort* XTp = XT + (size_t)(tsr * 8 + bg) * (HWP * 192);
    ushort* ob = t1s + (size_t)(tsr * 8 + bg) * QKV_B;

    // ---- stage all X chunks once (paired-row swizzle, proven) ----
    #pragma unroll
    for (int ck = 0; ck < 6; ck++) {
        const int k0 = ck * 32;
        #pragma unroll
        for (int i = 0; i < 2; i++) {
            int u = i * 512 + t;                // 1024 units: 256 rows x 4 units
            int rp = u >> 3;
            int p = (u & 7) ^ (rp & 7);
            int r = (rp << 1) | (p >> 2);
            int c = p & 3;
            const ushort* gx = XTp + (size_t)(n0 + r) * 192 + k0 + c * 8;
            __builtin_amdgcn_global_load_lds(AS1(gx), AS3(&Xres[ck][(size_t)(i * 512 + t) * 8]), 16, 0, 0);
        }
    }
    __syncthreads();                 // X resident

    // W fragment row for this thread (fixed across mi): rows wm*64+m*16+fr
    const int wrow[4] = { wm * 64 + 0 * 16 + fr, wm * 64 + 1 * 16 + fr,
                          wm * 64 + 2 * 16 + fr, wm * 64 + 3 * 16 + fr };

    for (int mi = 0; mi < 5; mi++) {
        // preload all 24 W fragments for this mi into registers (L2-hot)
        bf16x8 wf[6][4];
        #pragma unroll
        for (int ck = 0; ck < 6; ck++)
            #pragma unroll
            for (int m = 0; m < 4; m++)
                wf[ck][m] = *(const bf16x8*)&Wc[(size_t)(mi * 128 + wrow[m]) * 192 + ck * 32 + kg * 8];

        f32x4 acc[4][4] = {};
        #pragma unroll
        for (int ck = 0; ck < 6; ck++) {
            bf16x8 bfr[4];
            #pragma unroll
            for (int n = 0; n < 4; n++) {
                int R = wn * 64 + n * 16 + fr;  // [0,256)
                int unit = (R >> 1) * 8 + ((((R & 1) << 2) | kg) ^ ((R >> 1) & 7));
                bfr[n] = *(const bf16x8*)&Xres[ck][unit * 8];
            }
            #pragma unroll
            for (int m = 0; m < 4; m++)
                #pragma unroll
                for (int n = 0; n < 4; n++)
                    acc[m][n] = __builtin_amdgcn_mfma_f32_16x16x32_bf16(wf[ck][m], bfr[n], acc[m][n], 0, 0, 0);
        }

        // epilogue for this mi: two 128x128 half-tiles via E (proven)
        const int m0 = mi * 128;
        #pragma unroll
        for (int hf = 0; hf < 2; hf++) {
            if (hf) __syncthreads();
            if ((wn >> 1) == hf) {
                int wn2 = wn & 1;
                #pragma unroll
                for (int m = 0; m < 4; m++) {
                    int rl = wm * 64 + m * 16 + kg * 4;
                    #pragma unroll
                    for (int n = 0; n < 4; n++) {
                        int cl = wn2 * 64 + n * 16 + fr;
                        #pragma unroll
                        for (int r = 0; r < 4; r++)
                            E[rl + r][cl] = f2bf(acc[m][n][r]);
                    }
                }
            }
            __syncthreads();
            #pragma unroll
            for (int i = 0; i < 4; i++) {
                int u = t + 512 * i;            // 2048: 128 rows x 16 col-units
                int row = u >> 4, c8 = u & 15;
                int oc = m0 + row;
                if (oc < C3)
                    *(bf16x8*)&ob[(size_t)oc * HWP + n0 + hf * 128 + c8 * 8] =
                        *(bf16x8*)&E[row][c8 * 8];
            }
        }
        __syncthreads();             // E reads done before next mi overwrites
    }
}

// ============================================================
// depthwise 3x3, both tensors (grid 9216). 4x4 register-blocked rolling
// window (proven). q/k bf16 + fused L2 norm; v bf16.
// ============================================================
__global__ __launch_bounds__(256) void dw3x3_kernel(const ushort* __restrict__ inp,
    const float* __restrict__ wd,
    ushort* __restrict__ qh0, ushort* __restrict__ vv0, float* __restrict__ inv0)
{
    __shared__ float P[66][76];
    const int bcg = blockIdx.x;
    const int tsr = bcg / (BB * C3);
    const int bc = bcg - tsr * (BB * C3);       // b*576 + ch
    const int b = bc / C3, ch = bc % C3;
    const int t = threadIdx.x;
    const ushort* ip = inp + (size_t)tsr * ((size_t)BB * QKV_B) + (size_t)bc * HWP;
    ushort* qh = qh0 + (size_t)tsr * 12582912;
    ushort* vv = vv0 + (size_t)tsr * 6291456;
    float* inv = inv0 + (size_t)tsr * 3072;
    float wr[9];
    #pragma unroll
    for (int k = 0; k < 9; k++) wr[k] = wd[ch * 9 + k];
    for (int i = t; i < 66 * 76; i += 256) ((float*)P)[i] = 0.f;
    __syncthreads();
    #pragma unroll
    for (int i = 0; i < 2; i++) {
        int u = t + 256 * i;            // 512 units of 8 px
        int y = u >> 3, x0 = (u & 7) * 8;
        bf16x8 v8 = *(const bf16x8*)&ip[u * 8];
        float f0 = bf2f((ushort)v8[0]), f1 = bf2f((ushort)v8[1]);
        float f2 = bf2f((ushort)v8[2]), f3 = bf2f((ushort)v8[3]);
        float f4 = bf2f((ushort)v8[4]), f5 = bf2f((ushort)v8[5]);
        float f6 = bf2f((ushort)v8[6]), f7 = bf2f((ushort)v8[7]);
        *(float4*)&P[1 + y][4 + x0]     = make_float4(f0, f1, f2, f3);
        *(float4*)&P[1 + y][4 + x0 + 4] = make_float4(f4, f5, f6, f7);
    }
    __syncthreads();

    const int tx = t & 15, ty = t >> 4;
    const int x0 = tx * 4, y0 = ty * 4;

    float ssum = 0.f;
    float4 a0 = *(float4*)&P[y0][x0], b0 = *(float4*)&P[y0][x0 + 4], c0 = *(float4*)&P[y0][x0 + 8];
    float4 a1 = *(float4*)&P[y0 + 1][x0], b1 = *(float4*)&P[y0 + 1][x0 + 4], c1 = *(float4*)&P[y0 + 1][x0 + 8];
    #pragma unroll
    for (int r = 0; r < 4; r++) {
        float4 a2 = *(float4*)&P[y0 + r + 2][x0];
        float4 b2 = *(float4*)&P[y0 + r + 2][x0 + 4];
        float4 c2 = *(float4*)&P[y0 + r + 2][x0 + 8];
        float res[4] = {0.f, 0.f, 0.f, 0.f};
        {
            float e0 = a0.w, e1 = b0.x, e2 = b0.y, e3 = b0.z, e4 = b0.w, e5 = c0.x;
            res[0] += wr[0]*e0 + wr[1]*e1 + wr[2]*e2;
            res[1] += wr[0]*e1 + wr[1]*e2 + wr[2]*e3;
            res[2] += wr[0]*e2 + wr[1]*e3 + wr[2]*e4;
            res[3] += wr[0]*e3 + wr[1]*e4 + wr[2]*e5;
        }
        {
            float e0 = a1.w, e1 = b1.x, e2 = b1.y, e3 = b1.z, e4 = b1.w, e5 = c1.x;
            res[0] += wr[3]*e0 + wr[4]*e1 + wr[5]*e2;
            res[1] += wr[3]*e1 + wr[4]*e2 + wr[5]*e3;
            res[2] += wr[3]*e2 + wr[4]*e3 + wr[5]*e4;
            res[3] += wr[3]*e3 + wr[4]*e4 + wr[5]*e5;
        }
        {
            float e0 = a2.w, e1 = b2.x, e2 = b2.y, e3 = b2.z, e4 = b2.w, e5 = c2.x;
            res[0] += wr[6]*e0 + wr[7]*e1 + wr[8]*e2;
            res[1] += wr[6]*e1 + wr[7]*e2 + wr[8]*e3;
            res[2] += wr[6]*e2 + wr[7]*e3 + wr[8]*e4;
            res[3] += wr[6]*e3 + wr[7]*e4 + wr[8]*e5;
        }
        #pragma unroll
        for (int k = 0; k < 4; k++) ssum += res[k] * res[k];
        int px = (y0 + r) * WW + x0;
        if (ch < 384) {
            size_t base = ((size_t)b * 384 + ch) * HWP + px;
            *(ushort4*)&qh[base] = make_ushort4(f2bf(res[0]), f2bf(res[1]),
                                                f2bf(res[2]), f2bf(res[3]));
        } else {
            size_t base = ((size_t)b * CC + (ch - 384)) * HWP + px;
            *(ushort4*)&vv[base] = make_ushort4(f2bf(res[0]), f2bf(res[1]),
                                                f2bf(res[2]), f2bf(res[3]));
        }
        a0 = a1; b0 = b1; c0 = c1;
        a1 = a2; b1 = b2; c1 = c2;
    }
    if (ch < 384) {
        #pragma unroll
        for (int off = 32; off > 0; off >>= 1) ssum += __shfl_down(ssum, off);
        __shared__ float red[4];
        if ((t & 63) == 0) red[t >> 6] = ssum;
        __syncthreads();
        if (t == 0) {
            float tot = red[0] + red[1] + red[2] + red[3];
            inv[b * 384 + ch] = 1.f / fmaxf(sqrtf(tot), 1e-12f);
        }
    }
}

// ============================================================
// stacked Gram via MFMA, single bf16 (proven, unchanged)
// ============================================================
__global__ __launch_bounds__(256) void gram_mfma(const ushort* __restrict__ qhx,
    const ushort* __restrict__ qhy, float* __restrict__ spart)
{
    __shared__ __align__(16) ushort As[96 * 64];
    __shared__ __align__(16) ushort Bs[96 * 64];
    const int chunk = blockIdx.x, bh = blockIdx.y;
    const int b = bh >> 2, h = bh & 3;
    const int t = threadIdx.x;
    const int lane = t & 63, w = t >> 6;
    const int wm = w >> 1, wn = w & 1;
    const int fr = lane & 15, kg = lane >> 4;

    const size_t qbase = ((size_t)b * 384 + h * DH) * HWP;
    const size_t kbase = ((size_t)b * 384 + 192 + h * DH) * HWP;

    f32x4 acc[3][3] = {};

    for (int ks = 0; ks < 8; ks++) {
        const int n0 = chunk * 512 + ks * 64;
        #pragma unroll
        for (int i = 0; i < 3; i++) {
            int u = i * 256 + w * 64 + lane;
            int r = u >> 3, c = u & 7;
            int cs = c ^ (r & 7);
            const ushort* ga = ((r < DH) ? (qhx + qbase + (size_t)r * HWP)
                                         : (qhy + qbase + (size_t)(r - DH) * HWP))
                               + n0 + cs * 8;
            __builtin_amdgcn_global_load_lds(AS1(ga), AS3(&As[(size_t)(i * 4 + w) * 512]), 16, 0, 0);
            const ushort* gb = ((r < DH) ? (qhx + kbase + (size_t)r * HWP)
                                         : (qhy + kbase + (size_t)(r - DH) * HWP))
                               + n0 + cs * 8;
            __builtin_amdgcn_global_load_lds(AS1(gb), AS3(&Bs[(size_t)(i * 4 + w) * 512]), 16, 0, 0);
        }
        __syncthreads();
        #pragma unroll
        for (int kq = 0; kq < 8; kq += 4) {
            bf16x8 af[3], bfr[3];
            #pragma unroll
            for (int m = 0; m < 3; m++) {
                int R = wm * DH + m * 16 + fr;
                int unit = R * 8 + ((kq + kg) ^ (R & 7));
                af[m] = *(const bf16x8*)&As[unit * 8];
            }
            #pragma unroll
            for (int n = 0; n < 3; n++) {
                int R = wn * DH + n * 16 + fr;
                int unit = R * 8 + ((kq + kg) ^ (R & 7));
                bfr[n] = *(const bf16x8*)&Bs[unit * 8];
            }
            #pragma unroll
            for (int m = 0; m < 3; m++)
                #pragma unroll
                for (int n = 0; n < 3; n++)
                    acc[m][n] = __builtin_amdgcn_mfma_f32_16x16x32_bf16(af[m], bfr[n], acc[m][n], 0, 0, 0);
        }
        __syncthreads();
    }

    float* sp = spart + ((size_t)chunk * 32 + bh) * 9216;
    #pragma unroll
    for (int m = 0; m < 3; m++) {
        int row = wm * DH + m * 16 + kg * 4;
        #pragma unroll
        for (int n = 0; n < 3; n++) {
            int col = wn * DH + n * 16 + fr;
            #pragma unroll
            for (int r = 0; r < 4; r++)
                sp[(row + r) * 96 + col] = acc[m][n][r];
        }
    }
}

// ============================================================
// combine split-K partials, scale, softmax; emit single-bf16 coefficient
// matrix M'(96 x 128): two BK=64 chunks [Mx|My], cols 48..63 of each zeroed
// ============================================================
__global__ __launch_bounds__(256) void softmax_kernel(const float* __restrict__ spart,
    const float* __restrict__ invx, const float* __restrict__ invy,
    const float* __restrict__ temp, ushort* __restrict__ mpp)
{
    __shared__ float G[96][97];
    const int bh = blockIdx.x, b = bh >> 2, h = bh & 3;
    const int t = threadIdx.x;
    const float ts = temp[h];
    for (int i = 0; i < 36; i++) {
        int f = t + 256 * i;
        float s = 0.f;
        #pragma unroll
        for (int cch = 0; cch < 8; cch++)
            s += spart[((size_t)cch * 32 + bh) * 9216 + f];
        int r = f / 96, c = f % 96;
        float iq = (r < DH) ? invx[b*384 + h*DH + r] : invy[b*384 + h*DH + (r-DH)];
        float ik = (c < DH) ? invx[b*384 + CC + h*DH + c] : invy[b*384 + CC + h*DH + (c-DH)];
        G[r][c] = s * iq * ik * ts;
    }
    __syncthreads();
    if (t < 192) {
        int r = t >> 1, hf = t & 1;
        float* rowp = &G[r][hf * DH];
        float m = rowp[0];
        for (int i = 1; i < DH; i++) m = fmaxf(m, rowp[i]);
        float s = 0.f;
        for (int i = 0; i < DH; i++) { float e = __expf(rowp[i] - m); rowp[i] = e; s += e; }
        float inv = 1.f / s;
        for (int i = 0; i < DH; i++) rowp[i] *= inv;
    }
    __syncthreads();
    ushort* mo = mpp + (size_t)bh * 96 * 128;
    for (int i = 0; i < 12; i++) {
        int f = t + 256 * i;                 // 96 rows x 32 pad cols
        int r = f / 32, p = f % 32;
        int ch = p >> 4, j = p & 15;
        mo[(size_t)r * 128 + ch * 64 + 48 + j] = 0;
    }
    for (int i = 0; i < 36; i++) {
        int f = t + 256 * i;
        int r = f / 96, c = f % 96;
        float v;
        if (c < DH) v = (r < DH) ? G[DH + r][c] : G[r - DH][c];
        else        v = G[r][c];
        ushort hi = f2bf(v);
        if (c < DH) mo[(size_t)r * 128 + c] = hi;
        else        mo[(size_t)r * 128 + 64 + (c - DH)] = hi;
    }
}

// ============================================================
// output GEMM via MFMA (proven, unchanged)
// ============================================================
__global__ __launch_bounds__(256) void outmm_mfma(const ushort* __restrict__ VTx,
    const ushort* __restrict__ VTy, const ushort* __restrict__ mpp,
    float* __restrict__ out)
{
    __shared__ __align__(16) ushort As[96 * 64];
    __shared__ __align__(16) ushort Bs[128 * 64];
    const int t = threadIdx.x;
    const int lane = t & 63, w = t >> 6;
    const int wm = w >> 1, wn = w & 1;
    const int fr = lane & 15, kg = lane >> 4;
    const int nc = blockIdx.x, bh = blockIdx.y;
    const int b = bh >> 2, h = bh & 3;
    const int n0 = nc * 128;
    const ushort* mp = mpp + (size_t)bh * 96 * 128;

    f32x4 acc[3][4] = {};

    for (int kc = 0; kc < 2; kc++) {
        const ushort* Vsrc = kc ? VTy : VTx;
        const int coff = h * DH;
        const int aoff = kc * 64;
        #pragma unroll
        for (int i = 0; i < 3; i++) {
            int u = i * 256 + w * 64 + lane;
            int r = u >> 3, c = u & 7;
            int cs = c ^ (r & 7);
            const ushort* ga = mp + (size_t)r * 128 + aoff + cs * 8;
            __builtin_amdgcn_global_load_lds(AS1(ga), AS3(&As[(size_t)(i * 4 + w) * 512]), 16, 0, 0);
        }
        #pragma unroll
        for (int i = 0; i < 4; i++) {
            int u = i * 256 + w * 64 + lane;
            int r = u >> 3, c = u & 7;
            int cs = c ^ (r & 7);
            int c8 = coff + cs * 8;
            if (c8 >= 192) c8 -= 192;       // wrap: lands on zero-A K-rows
            const ushort* gb = Vsrc + ((size_t)(b * HWP + n0 + r)) * 192 + c8;
            __builtin_amdgcn_global_load_lds(AS1(gb), AS3(&Bs[(size_t)(i * 4 + w) * 512]), 16, 0, 0);
        }
        __syncthreads();
        #pragma unroll
        for (int kq = 0; kq < 8; kq += 4) {
            bf16x8 af[3], bfr[4];
            #pragma unroll
            for (int m = 0; m < 3; m++) {
                int R = wm * DH + m * 16 + fr;
                int unit = R * 8 + ((kq + kg) ^ (R & 7));
                af[m] = *(const bf16x8*)&As[unit * 8];
            }
            #pragma unroll
            for (int n = 0; n < 4; n++) {
                int R = wn * 64 + n * 16 + fr;
                int unit = R * 8 + ((kq + kg) ^ (R & 7));
                bfr[n] = *(const bf16x8*)&Bs[unit * 8];
            }
            #pragma unroll
            for (int m = 0; m < 3; m++)
                #pragma unroll
                for (int n = 0; n < 4; n++)
                    acc[m][n] = __builtin_amdgcn_mfma_f32_16x16x32_bf16(af[m], bfr[n], acc[m][n], 0, 0, 0);
        }
        __syncthreads();
    }

    #pragma unroll
    for (int m = 0; m < 3; m++) {
        int row = wm * DH + m * 16 + kg * 4;
        #pragma unroll
        for (int n = 0; n < 4; n++) {
            int col = n0 + wn * 64 + n * 16 + fr;
            #pragma unroll
            for (int r = 0; r < 4; r++) {
                int rr = row + r;
                float* dst = (rr < DH)
                    ? (out + (size_t)b * X_B + (h * DH + rr) * HWP + col)
                    : (out + OUT_HALF + (size_t)b * X_B + (h * DH + rr - DH) * HWP + col);
                *dst = acc[m][n][r];
            }
        }
    }
}

// ============================================================
extern "C" void kernel_launch(void* const* d_in, const int* in_sizes, int n_in,
                              void* d_out, int out_size, void* d_ws, size_t ws_size,
                              hipStream_t stream)
{
    const float* x  = (const float*)d_in[0];
    const float* y  = (const float*)d_in[1];
    const float* wq = (const float*)d_in[2];
    const float* wd = (const float*)d_in[3];
    const float* tp = (const float*)d_in[4];
    float* out = (float*)d_out;
    float* ws = (float*)d_ws;

    // ---- workspace layout (float units), total ~176 MB of 256 MB ----
    ushort* qh0 = (ushort*)ws;
    float*  v0f = ws + 12582912;
    ushort* v0  = (ushort*)v0f;
    float*  t10 = ws + 12582912 + 6291456;
    ushort* t1s = (ushort*)t10;
    ushort* XT  = (ushort*)(ws + 12582912 + 6291456 + 18874368);
    ushort* Wc  = (ushort*)(ws + 12582912 + 6291456 + 18874368 + 6291456);
    float*  inv0 = ws + 12582912 + 6291456 + 18874368 + 6291456 + 61440;
    float*  invx = inv0;
    float*  invy = inv0 + 3072;
    // aliases over t1 region (dead after dw):
    ushort* VTx  = t1s;
    ushort* VTy  = (ushort*)(t10 + 3145728);
    float*  spart = t10 + 6291456;
    ushort* Mpp  = (ushort*)(t10 + 6291456 + 2359296);
    ushort* qhx = qh0;
    ushort* qhy = qh0 + 12582912;

    wconvert_kernel<<<120, 256, 0, stream>>>(wq, Wc);

    // both tensors: convert -> conv -> dw (one dispatch each)
    convert_single_kernel<<<dim3(64, 3, 16), 256, 0, stream>>>(x, y, XT);
    conv1x1_mfma<<<256, 512, 0, stream>>>(XT, Wc, t1s);
    dw3x3_kernel<<<2 * BB * C3, 256, 0, stream>>>(t1s, wd, qh0, v0, inv0);

    // transpose v (both tensors) into dead t1 region
    vtrans_kernel<<<dim3(64, 3, 16), 256, 0, stream>>>(v0, VTx);

    gram_mfma<<<dim3(8, 32), 256, 0, stream>>>(qhx, qhy, spart);
    softmax_kernel<<<32, 256, 0, stream>>>(spart, invx, invy, tp, Mpp);
    outmm_mfma<<<dim3(HWP / 128, 32), 256, 0, stream>>>(VTx, VTy, Mpp, out);
}

// Round 18
// 139.339 us; speedup vs baseline: 1.0801x; 1.0801x over previous
//
#include <hip/hip_runtime.h>

// ---- problem constants ----
#define CC   192                 // C
#define C3   576                 // 3C
#define HH   64
#define WW   64
#define HWP  4096                // H*W
#define BB   8
#define DH   48                  // C/HEADS
#define QKV_B (C3*HWP)           // elements per batch of conv-out tensor
#define X_B   (CC*HWP)
#define OUT_HALF ((size_t)BB*X_B)

typedef short bf16x8 __attribute__((ext_vector_type(8)));
typedef float f32x4  __attribute__((ext_vector_type(4)));

#define AS1(p) ((__attribute__((address_space(1))) void*)(p))
#define AS3(p) ((__attribute__((address_space(3))) void*)(p))

__device__ __forceinline__ ushort f2bf(float v) {
    union { float f; unsigned u; } a; a.f = v;
    unsigned r = a.u + 0x7FFF + ((a.u >> 16) & 1);   // RNE
    return (ushort)(r >> 16);
}
__device__ __forceinline__ float bf2f(ushort h) {
    union { float f; unsigned u; } a; a.u = ((unsigned)h) << 16; return a.f;
}

// ============================================================
// {x,y} (b,192,4096) fp32 -> XT (tsr,b,4096,192) bf16 single. z in [0,16).
// ============================================================
__global__ __launch_bounds__(256) void convert_single_kernel(const float* __restrict__ x,
    const float* __restrict__ y, ushort* __restrict__ xt)
{
    __shared__ float L[64][65];
    const int n0 = blockIdx.x * 64, c0 = blockIdx.y * 64, z = blockIdx.z;
    const int t = threadIdx.x;
    const float* ip = ((z < 8) ? x : y) + (size_t)(z & 7) * X_B;
    #pragma unroll
    for (int i = 0; i < 16; i++) {
        int e = t + 256 * i;
        int r = e >> 6, col = e & 63;
        L[r][col] = ip[(size_t)(c0 + r) * HWP + n0 + col];
    }
    __syncthreads();
    #pragma unroll
    for (int i = 0; i < 4; i++) {
        int e = t + 256 * i;
        int n = e >> 4, c4 = e & 15;
        ushort hi[4];
        #pragma unroll
        for (int j = 0; j < 4; j++)
            hi[j] = f2bf(L[c4 * 4 + j][n]);
        size_t base = ((size_t)z * HWP + n0 + n) * 192 + c0 + c4 * 4;
        *(ushort4*)&xt[base] = make_ushort4(hi[0], hi[1], hi[2], hi[3]);
    }
}

// ============================================================
// v bf16 (16 batch-slices,192,4096) -> VT (...,4096,192) transpose. z in [0,16).
// ============================================================
__global__ __launch_bounds__(256) void vtrans_kernel(const ushort* __restrict__ in,
    ushort* __restrict__ vt)
{
    __shared__ __align__(16) ushort L[64][72];
    const int n0 = blockIdx.x * 64, c0 = blockIdx.y * 64, z = blockIdx.z;
    const int t = threadIdx.x;
    const ushort* ip = in + (size_t)z * X_B;
    #pragma unroll
    for (int i = 0; i < 2; i++) {
        int e = t + 256 * i;            // 512 units of 8 ushorts
        int r = e >> 3, u8 = e & 7;
        *(bf16x8*)&L[r][u8 * 8] = *(const bf16x8*)&ip[(size_t)(c0 + r) * HWP + n0 + u8 * 8];
    }
    __syncthreads();
    #pragma unroll
    for (int i = 0; i < 4; i++) {
        int e = t + 256 * i;            // 1024: 64 n x 16 c4
        int n = e >> 4, c4 = e & 15;
        ushort o[4];
        #pragma unroll
        for (int j = 0; j < 4; j++) o[j] = L[c4 * 4 + j][n];
        *(ushort4*)&vt[((size_t)z * HWP + n0 + n) * 192 + c0 + c4 * 4] =
            make_ushort4(o[0], o[1], o[2], o[3]);
    }
}

// ============================================================
// w_qkv -> Wc(640,192) bf16 SINGLE, zero-padded rows 576..639
// ============================================================
__global__ __launch_bounds__(256) void wconvert_kernel(const float* __restrict__ wq,
    ushort* __restrict__ wc)
{
    int e = (blockIdx.x * 256 + threadIdx.x) * 4;    // 640*192 total
    int oc = e / 192, k = e % 192;
    ushort o[4] = {0, 0, 0, 0};
    if (oc < C3) {
        #pragma unroll
        for (int j = 0; j < 4; j++)
            o[j] = f2bf(wq[oc * CC + k + j]);
    }
    *(ushort4*)&wc[e] = make_ushort4(o[0], o[1], o[2], o[3]);
}

// ============================================================
// conv1x1 via MFMA, X-RESIDENT schedule (round-16 proven, 43.0 us):
// block = (tsr,b,nt of 256 cols), stages all 6 X chunks (96 KB) ONCE, then
// loops mi=0..4 streaming W (8 KB dbuf, prefetch chained across mi).
// Grid 256 blocks x 512 thr (1 block/CU). Paired-row swizzle + E epilogue.
// ============================================================
__global__ __launch_bounds__(512) void conv1x1_mfma(const ushort* __restrict__ XT,
    const ushort* __restrict__ Wc, ushort* __restrict__ t1s)
{
    __shared__ __align__(16) ushort Xres[6][1024 * 8];  // 6 x 16 KB resident
    __shared__ __align__(16) ushort Wsb[2][512 * 8];    // 2 x 8 KB dbuf
    __shared__ __align__(16) ushort E[128][128];        // 32 KB epilogue
    const int t = threadIdx.x;
    const int lane = t & 63, w = t >> 6;
    const int wm = w >> 2, wn = w & 3;
    const int fr = lane & 15, kg = lane >> 4;
    const int g = blockIdx.x;
    const int bg = g & 7, s = g >> 3;           // s in [0,32)
    const int tsr = s >> 4;
    const int nt = s & 15;
    const int n0 = nt * 256;
    const ushort* XTp = XT + (size_t)(tsr * 8 + bg) * (HWP * 192);
    ushort* ob = t1s + (size_t)(tsr * 8 + bg) * QKV_B;

    // ---- stage all X chunks (linear dest per chunk, paired-row swizzle) ----
    #pragma unroll
    for (int ck = 0; ck < 6; ck++) {
        const int k0 = ck * 32;
        #pragma unroll
        for (int i = 0; i < 2; i++) {
            int u = i * 512 + t;                // 1024 units: 256 rows x 4 units
            int rp = u >> 3;
            int p = (u & 7) ^ (rp & 7);
            int r = (rp << 1) | (p >> 2);
            int c = p & 3;
            const ushort* gx = XTp + (size_t)(n0 + r) * 192 + k0 + c * 8;
            __builtin_amdgcn_global_load_lds(AS1(gx), AS3(&Xres[ck][(size_t)(i * 512 + t) * 8]), 16, 0, 0);
        }
    }

    auto STAGE_W = [&](int buf, int mi, int ck) {
        const int k0 = ck * 32;
        int u = t;                              // 512 units: 128 rows x 4 units
        int rp = u >> 3;
        int p = (u & 7) ^ (rp & 7);
        int r = (rp << 1) | (p >> 2);
        int c = p & 3;
        const ushort* gw = Wc + (size_t)(mi * 128 + r) * 192 + k0 + c * 8;
        __builtin_amdgcn_global_load_lds(AS1(gw), AS3(&Wsb[buf][(size_t)t * 8]), 16, 0, 0);
    };

    STAGE_W(0, 0, 0);
    __syncthreads();                 // X + W(0,0) resident
    int cur = 0;

    for (int mi = 0; mi < 5; mi++) {
        f32x4 acc[4][4] = {};
        for (int ck = 0; ck < 6; ck++) {
            if (mi * 6 + ck < 29) {
                int nmi = (ck == 5) ? mi + 1 : mi;
                int nck = (ck == 5) ? 0 : ck + 1;
                STAGE_W(cur ^ 1, nmi, nck);     // prefetch next W chunk
            }
            bf16x8 afh[4], bfr[4];
            #pragma unroll
            for (int m = 0; m < 4; m++) {
                int R = wm * 64 + m * 16 + fr;  // [0,128)
                int unit = (R >> 1) * 8 + ((((R & 1) << 2) | kg) ^ ((R >> 1) & 7));
                afh[m] = *(const bf16x8*)&Wsb[cur][unit * 8];
            }
            #pragma unroll
            for (int n = 0; n < 4; n++) {
                int R = wn * 64 + n * 16 + fr;  // [0,256)
                int unit = (R >> 1) * 8 + ((((R & 1) << 2) | kg) ^ ((R >> 1) & 7));
                bfr[n] = *(const bf16x8*)&Xres[ck][unit * 8];
            }
            #pragma unroll
            for (int m = 0; m < 4; m++)
                #pragma unroll
                for (int n = 0; n < 4; n++)
                    acc[m][n] = __builtin_amdgcn_mfma_f32_16x16x32_bf16(afh[m], bfr[n], acc[m][n], 0, 0, 0);
            __syncthreads();         // W prefetch done + WAR safe
            cur ^= 1;
        }

        // epilogue for this mi: two 128x128 half-tiles via E
        const int m0 = mi * 128;
        #pragma unroll
        for (int hf = 0; hf < 2; hf++) {
            if (hf) __syncthreads();
            if ((wn >> 1) == hf) {
                int wn2 = wn & 1;
                #pragma unroll
                for (int m = 0; m < 4; m++) {
                    int rl = wm * 64 + m * 16 + kg * 4;
                    #pragma unroll
                    for (int n = 0; n < 4; n++) {
                        int cl = wn2 * 64 + n * 16 + fr;
                        #pragma unroll
                        for (int r = 0; r < 4; r++)
                            E[rl + r][cl] = f2bf(acc[m][n][r]);
                    }
                }
            }
            __syncthreads();
            #pragma unroll
            for (int i = 0; i < 4; i++) {
                int u = t + 512 * i;            // 2048: 128 rows x 16 col-units
                int row = u >> 4, c8 = u & 15;
                int oc = m0 + row;
                if (oc < C3)
                    *(bf16x8*)&ob[(size_t)oc * HWP + n0 + hf * 128 + c8 * 8] =
                        *(bf16x8*)&E[row][c8 * 8];
            }
        }
        __syncthreads();             // E reads done before next mi overwrites
    }
}

// ============================================================
// depthwise 3x3, both tensors (grid 9216). 4x4 register-blocked rolling
// window (proven). q/k bf16 + fused L2 norm; v bf16.
// ============================================================
__global__ __launch_bounds__(256) void dw3x3_kernel(const ushort* __restrict__ inp,
    const float* __restrict__ wd,
    ushort* __restrict__ qh0, ushort* __restrict__ vv0, float* __restrict__ inv0)
{
    __shared__ float P[66][76];
    const int bcg = blockIdx.x;
    const int tsr = bcg / (BB * C3);
    const int bc = bcg - tsr * (BB * C3);       // b*576 + ch
    const int b = bc / C3, ch = bc % C3;
    const int t = threadIdx.x;
    const ushort* ip = inp + (size_t)tsr * ((size_t)BB * QKV_B) + (size_t)bc * HWP;
    ushort* qh = qh0 + (size_t)tsr * 12582912;
    ushort* vv = vv0 + (size_t)tsr * 6291456;
    float* inv = inv0 + (size_t)tsr * 3072;
    float wr[9];
    #pragma unroll
    for (int k = 0; k < 9; k++) wr[k] = wd[ch * 9 + k];
    for (int i = t; i < 66 * 76; i += 256) ((float*)P)[i] = 0.f;
    __syncthreads();
    #pragma unroll
    for (int i = 0; i < 2; i++) {
        int u = t + 256 * i;            // 512 units of 8 px
        int y = u >> 3, x0 = (u & 7) * 8;
        bf16x8 v8 = *(const bf16x8*)&ip[u * 8];
        float f0 = bf2f((ushort)v8[0]), f1 = bf2f((ushort)v8[1]);
        float f2 = bf2f((ushort)v8[2]), f3 = bf2f((ushort)v8[3]);
        float f4 = bf2f((ushort)v8[4]), f5 = bf2f((ushort)v8[5]);
        float f6 = bf2f((ushort)v8[6]), f7 = bf2f((ushort)v8[7]);
        *(float4*)&P[1 + y][4 + x0]     = make_float4(f0, f1, f2, f3);
        *(float4*)&P[1 + y][4 + x0 + 4] = make_float4(f4, f5, f6, f7);
    }
    __syncthreads();

    const int tx = t & 15, ty = t >> 4;
    const int x0 = tx * 4, y0 = ty * 4;

    float ssum = 0.f;
    float4 a0 = *(float4*)&P[y0][x0], b0 = *(float4*)&P[y0][x0 + 4], c0 = *(float4*)&P[y0][x0 + 8];
    float4 a1 = *(float4*)&P[y0 + 1][x0], b1 = *(float4*)&P[y0 + 1][x0 + 4], c1 = *(float4*)&P[y0 + 1][x0 + 8];
    #pragma unroll
    for (int r = 0; r < 4; r++) {
        float4 a2 = *(float4*)&P[y0 + r + 2][x0];
        float4 b2 = *(float4*)&P[y0 + r + 2][x0 + 4];
        float4 c2 = *(float4*)&P[y0 + r + 2][x0 + 8];
        float res[4] = {0.f, 0.f, 0.f, 0.f};
        {
            float e0 = a0.w, e1 = b0.x, e2 = b0.y, e3 = b0.z, e4 = b0.w, e5 = c0.x;
            res[0] += wr[0]*e0 + wr[1]*e1 + wr[2]*e2;
            res[1] += wr[0]*e1 + wr[1]*e2 + wr[2]*e3;
            res[2] += wr[0]*e2 + wr[1]*e3 + wr[2]*e4;
            res[3] += wr[0]*e3 + wr[1]*e4 + wr[2]*e5;
        }
        {
            float e0 = a1.w, e1 = b1.x, e2 = b1.y, e3 = b1.z, e4 = b1.w, e5 = c1.x;
            res[0] += wr[3]*e0 + wr[4]*e1 + wr[5]*e2;
            res[1] += wr[3]*e1 + wr[4]*e2 + wr[5]*e3;
            res[2] += wr[3]*e2 + wr[4]*e3 + wr[5]*e4;
            res[3] += wr[3]*e3 + wr[4]*e4 + wr[5]*e5;
        }
        {
            float e0 = a2.w, e1 = b2.x, e2 = b2.y, e3 = b2.z, e4 = b2.w, e5 = c2.x;
            res[0] += wr[6]*e0 + wr[7]*e1 + wr[8]*e2;
            res[1] += wr[6]*e1 + wr[7]*e2 + wr[8]*e3;
            res[2] += wr[6]*e2 + wr[7]*e3 + wr[8]*e4;
            res[3] += wr[6]*e3 + wr[7]*e4 + wr[8]*e5;
        }
        #pragma unroll
        for (int k = 0; k < 4; k++) ssum += res[k] * res[k];
        int px = (y0 + r) * WW + x0;
        if (ch < 384) {
            size_t base = ((size_t)b * 384 + ch) * HWP + px;
            *(ushort4*)&qh[base] = make_ushort4(f2bf(res[0]), f2bf(res[1]),
                                                f2bf(res[2]), f2bf(res[3]));
        } else {
            size_t base = ((size_t)b * CC + (ch - 384)) * HWP + px;
            *(ushort4*)&vv[base] = make_ushort4(f2bf(res[0]), f2bf(res[1]),
                                                f2bf(res[2]), f2bf(res[3]));
        }
        a0 = a1; b0 = b1; c0 = c1;
        a1 = a2; b1 = b2; c1 = c2;
    }
    if (ch < 384) {
        #pragma unroll
        for (int off = 32; off > 0; off >>= 1) ssum += __shfl_down(ssum, off);
        __shared__ float red[4];
        if ((t & 63) == 0) red[t >> 6] = ssum;
        __syncthreads();
        if (t == 0) {
            float tot = red[0] + red[1] + red[2] + red[3];
            inv[b * 384 + ch] = 1.f / fmaxf(sqrtf(tot), 1e-12f);
        }
    }
}

// ============================================================
// stacked Gram via MFMA, single bf16 (proven, unchanged)
// ============================================================
__global__ __launch_bounds__(256) void gram_mfma(const ushort* __restrict__ qhx,
    const ushort* __restrict__ qhy, float* __restrict__ spart)
{
    __shared__ __align__(16) ushort As[96 * 64];
    __shared__ __align__(16) ushort Bs[96 * 64];
    const int chunk = blockIdx.x, bh = blockIdx.y;
    const int b = bh >> 2, h = bh & 3;
    const int t = threadIdx.x;
    const int lane = t & 63, w = t >> 6;
    const int wm = w >> 1, wn = w & 1;
    const int fr = lane & 15, kg = lane >> 4;

    const size_t qbase = ((size_t)b * 384 + h * DH) * HWP;
    const size_t kbase = ((size_t)b * 384 + 192 + h * DH) * HWP;

    f32x4 acc[3][3] = {};

    for (int ks = 0; ks < 8; ks++) {
        const int n0 = chunk * 512 + ks * 64;
        #pragma unroll
        for (int i = 0; i < 3; i++) {
            int u = i * 256 + w * 64 + lane;
            int r = u >> 3, c = u & 7;
            int cs = c ^ (r & 7);
            const ushort* ga = ((r < DH) ? (qhx + qbase + (size_t)r * HWP)
                                         : (qhy + qbase + (size_t)(r - DH) * HWP))
                               + n0 + cs * 8;
            __builtin_amdgcn_global_load_lds(AS1(ga), AS3(&As[(size_t)(i * 4 + w) * 512]), 16, 0, 0);
            const ushort* gb = ((r < DH) ? (qhx + kbase + (size_t)r * HWP)
                                         : (qhy + kbase + (size_t)(r - DH) * HWP))
                               + n0 + cs * 8;
            __builtin_amdgcn_global_load_lds(AS1(gb), AS3(&Bs[(size_t)(i * 4 + w) * 512]), 16, 0, 0);
        }
        __syncthreads();
        #pragma unroll
        for (int kq = 0; kq < 8; kq += 4) {
            bf16x8 af[3], bfr[3];
            #pragma unroll
            for (int m = 0; m < 3; m++) {
                int R = wm * DH + m * 16 + fr;
                int unit = R * 8 + ((kq + kg) ^ (R & 7));
                af[m] = *(const bf16x8*)&As[unit * 8];
            }
            #pragma unroll
            for (int n = 0; n < 3; n++) {
                int R = wn * DH + n * 16 + fr;
                int unit = R * 8 + ((kq + kg) ^ (R & 7));
                bfr[n] = *(const bf16x8*)&Bs[unit * 8];
            }
            #pragma unroll
            for (int m = 0; m < 3; m++)
                #pragma unroll
                for (int n = 0; n < 3; n++)
                    acc[m][n] = __builtin_amdgcn_mfma_f32_16x16x32_bf16(af[m], bfr[n], acc[m][n], 0, 0, 0);
        }
        __syncthreads();
    }

    float* sp = spart + ((size_t)chunk * 32 + bh) * 9216;
    #pragma unroll
    for (int m = 0; m < 3; m++) {
        int row = wm * DH + m * 16 + kg * 4;
        #pragma unroll
        for (int n = 0; n < 3; n++) {
            int col = wn * DH + n * 16 + fr;
            #pragma unroll
            for (int r = 0; r < 4; r++)
                sp[(row + r) * 96 + col] = acc[m][n][r];
        }
    }
}

// ============================================================
// combine split-K partials, scale, softmax; emit single-bf16 coefficient
// matrix M'(96 x 128): two BK=64 chunks [Mx|My], cols 48..63 of each zeroed
// ============================================================
__global__ __launch_bounds__(256) void softmax_kernel(const float* __restrict__ spart,
    const float* __restrict__ invx, const float* __restrict__ invy,
    const float* __restrict__ temp, ushort* __restrict__ mpp)
{
    __shared__ float G[96][97];
    const int bh = blockIdx.x, b = bh >> 2, h = bh & 3;
    const int t = threadIdx.x;
    const float ts = temp[h];
    for (int i = 0; i < 36; i++) {
        int f = t + 256 * i;
        float s = 0.f;
        #pragma unroll
        for (int cch = 0; cch < 8; cch++)
            s += spart[((size_t)cch * 32 + bh) * 9216 + f];
        int r = f / 96, c = f % 96;
        float iq = (r < DH) ? invx[b*384 + h*DH + r] : invy[b*384 + h*DH + (r-DH)];
        float ik = (c < DH) ? invx[b*384 + CC + h*DH + c] : invy[b*384 + CC + h*DH + (c-DH)];
        G[r][c] = s * iq * ik * ts;
    }
    __syncthreads();
    if (t < 192) {
        int r = t >> 1, hf = t & 1;
        float* rowp = &G[r][hf * DH];
        float m = rowp[0];
        for (int i = 1; i < DH; i++) m = fmaxf(m, rowp[i]);
        float s = 0.f;
        for (int i = 0; i < DH; i++) { float e = __expf(rowp[i] - m); rowp[i] = e; s += e; }
        float inv = 1.f / s;
        for (int i = 0; i < DH; i++) rowp[i] *= inv;
    }
    __syncthreads();
    ushort* mo = mpp + (size_t)bh * 96 * 128;
    for (int i = 0; i < 12; i++) {
        int f = t + 256 * i;                 // 96 rows x 32 pad cols
        int r = f / 32, p = f % 32;
        int ch = p >> 4, j = p & 15;
        mo[(size_t)r * 128 + ch * 64 + 48 + j] = 0;
    }
    for (int i = 0; i < 36; i++) {
        int f = t + 256 * i;
        int r = f / 96, c = f % 96;
        float v;
        if (c < DH) v = (r < DH) ? G[DH + r][c] : G[r - DH][c];
        else        v = G[r][c];
        ushort hi = f2bf(v);
        if (c < DH) mo[(size_t)r * 128 + c] = hi;
        else        mo[(size_t)r * 128 + 64 + (c - DH)] = hi;
    }
}

// ============================================================
// output GEMM via MFMA (proven, unchanged)
// ============================================================
__global__ __launch_bounds__(256) void outmm_mfma(const ushort* __restrict__ VTx,
    const ushort* __restrict__ VTy, const ushort* __restrict__ mpp,
    float* __restrict__ out)
{
    __shared__ __align__(16) ushort As[96 * 64];
    __shared__ __align__(16) ushort Bs[128 * 64];
    const int t = threadIdx.x;
    const int lane = t & 63, w = t >> 6;
    const int wm = w >> 1, wn = w & 1;
    const int fr = lane & 15, kg = lane >> 4;
    const int nc = blockIdx.x, bh = blockIdx.y;
    const int b = bh >> 2, h = bh & 3;
    const int n0 = nc * 128;
    const ushort* mp = mpp + (size_t)bh * 96 * 128;

    f32x4 acc[3][4] = {};

    for (int kc = 0; kc < 2; kc++) {
        const ushort* Vsrc = kc ? VTy : VTx;
        const int coff = h * DH;
        const int aoff = kc * 64;
        #pragma unroll
        for (int i = 0; i < 3; i++) {
            int u = i * 256 + w * 64 + lane;
            int r = u >> 3, c = u & 7;
            int cs = c ^ (r & 7);
            const ushort* ga = mp + (size_t)r * 128 + aoff + cs * 8;
            __builtin_amdgcn_global_load_lds(AS1(ga), AS3(&As[(size_t)(i * 4 + w) * 512]), 16, 0, 0);
        }
        #pragma unroll
        for (int i = 0; i < 4; i++) {
            int u = i * 256 + w * 64 + lane;
            int r = u >> 3, c = u & 7;
            int cs = c ^ (r & 7);
            int c8 = coff + cs * 8;
            if (c8 >= 192) c8 -= 192;       // wrap: lands on zero-A K-rows
            const ushort* gb = Vsrc + ((size_t)(b * HWP + n0 + r)) * 192 + c8;
            __builtin_amdgcn_global_load_lds(AS1(gb), AS3(&Bs[(size_t)(i * 4 + w) * 512]), 16, 0, 0);
        }
        __syncthreads();
        #pragma unroll
        for (int kq = 0; kq < 8; kq += 4) {
            bf16x8 af[3], bfr[4];
            #pragma unroll
            for (int m = 0; m < 3; m++) {
                int R = wm * DH + m * 16 + fr;
                int unit = R * 8 + ((kq + kg) ^ (R & 7));
                af[m] = *(const bf16x8*)&As[unit * 8];
            }
            #pragma unroll
            for (int n = 0; n < 4; n++) {
                int R = wn * 64 + n * 16 + fr;
                int unit = R * 8 + ((kq + kg) ^ (R & 7));
                bfr[n] = *(const bf16x8*)&Bs[unit * 8];
            }
            #pragma unroll
            for (int m = 0; m < 3; m++)
                #pragma unroll
                for (int n = 0; n < 4; n++)
                    acc[m][n] = __builtin_amdgcn_mfma_f32_16x16x32_bf16(af[m], bfr[n], acc[m][n], 0, 0, 0);
        }
        __syncthreads();
    }

    #pragma unroll
    for (int m = 0; m < 3; m++) {
        int row = wm * DH + m * 16 + kg * 4;
        #pragma unroll
        for (int n = 0; n < 4; n++) {
            int col = n0 + wn * 64 + n * 16 + fr;
            #pragma unroll
            for (int r = 0; r < 4; r++) {
                int rr = row + r;
                float* dst = (rr < DH)
                    ? (out + (size_t)b * X_B + (h * DH + rr) * HWP + col)
                    : (out + OUT_HALF + (size_t)b * X_B + (h * DH + rr - DH) * HWP + col);
                *dst = acc[m][n][r];
            }
        }
    }
}

// ============================================================
extern "C" void kernel_launch(void* const* d_in, const int* in_sizes, int n_in,
                              void* d_out, int out_size, void* d_ws, size_t ws_size,
                              hipStream_t stream)
{
    const float* x  = (const float*)d_in[0];
    const float* y  = (const float*)d_in[1];
    const float* wq = (const float*)d_in[2];
    const float* wd = (const float*)d_in[3];
    const float* tp = (const float*)d_in[4];
    float* out = (float*)d_out;
    float* ws = (float*)d_ws;

    // ---- workspace layout (float units), total ~176 MB of 256 MB ----
    ushort* qh0 = (ushort*)ws;
    float*  v0f = ws + 12582912;
    ushort* v0  = (ushort*)v0f;
    float*  t10 = ws + 12582912 + 6291456;
    ushort* t1s = (ushort*)t10;
    ushort* XT  = (ushort*)(ws + 12582912 + 6291456 + 18874368);
    ushort* Wc  = (ushort*)(ws + 12582912 + 6291456 + 18874368 + 6291456);
    float*  inv0 = ws + 12582912 + 6291456 + 18874368 + 6291456 + 61440;
    float*  invx = inv0;
    float*  invy = inv0 + 3072;
    // aliases over t1 region (dead after dw):
    ushort* VTx  = t1s;
    ushort* VTy  = (ushort*)(t10 + 3145728);
    float*  spart = t10 + 6291456;
    ushort* Mpp  = (ushort*)(t10 + 6291456 + 2359296);
    ushort* qhx = qh0;
    ushort* qhy = qh0 + 12582912;

    wconvert_kernel<<<120, 256, 0, stream>>>(wq, Wc);

    // both tensors: convert -> conv -> dw (one dispatch each)
    convert_single_kernel<<<dim3(64, 3, 16), 256, 0, stream>>>(x, y, XT);
    conv1x1_mfma<<<256, 512, 0, stream>>>(XT, Wc, t1s);
    dw3x3_kernel<<<2 * BB * C3, 256, 0, stream>>>(t1s, wd, qh0, v0, inv0);

    // transpose v (both tensors) into dead t1 region
    vtrans_kernel<<<dim3(64, 3, 16), 256, 0, stream>>>(v0, VTx);

    gram_mfma<<<dim3(8, 32), 256, 0, stream>>>(qhx, qhy, spart);
    softmax_kernel<<<32, 256, 0, stream>>>(spart, invx, invy, tp, Mpp);
    outmm_mfma<<<dim3(HWP / 128, 32), 256, 0, stream>>>(VTx, VTy, Mpp, out);
}

// Round 19
// 138.687 us; speedup vs baseline: 1.0851x; 1.0047x over previous
//
#include <hip/hip_runtime.h>

// ---- problem constants ----
#define CC   192                 // C
#define C3   576                 // 3C
#define HH   64
#define WW   64
#define HWP  4096                // H*W
#define BB   8
#define DH   48                  // C/HEADS
#define QKV_B (C3*HWP)           // elements per batch of conv-out tensor
#define X_B   (CC*HWP)
#define OUT_HALF ((size_t)BB*X_B)

typedef short bf16x8 __attribute__((ext_vector_type(8)));
typedef float f32x4  __attribute__((ext_vector_type(4)));

#define AS1(p) ((__attribute__((address_space(1))) void*)(p))
#define AS3(p) ((__attribute__((address_space(3))) void*)(p))

__device__ __forceinline__ ushort f2bf(float v) {
    union { float f; unsigned u; } a; a.f = v;
    unsigned r = a.u + 0x7FFF + ((a.u >> 16) & 1);   // RNE
    return (ushort)(r >> 16);
}
__device__ __forceinline__ float bf2f(ushort h) {
    union { float f; unsigned u; } a; a.u = ((unsigned)h) << 16; return a.f;
}

// ============================================================
// {x,y} (b,192,4096) fp32 -> XT (tsr,b,4096,192) bf16 single. z in [0,16).
// ============================================================
__global__ __launch_bounds__(256) void convert_single_kernel(const float* __restrict__ x,
    const float* __restrict__ y, ushort* __restrict__ xt)
{
    __shared__ float L[64][65];
    const int n0 = blockIdx.x * 64, c0 = blockIdx.y * 64, z = blockIdx.z;
    const int t = threadIdx.x;
    const float* ip = ((z < 8) ? x : y) + (size_t)(z & 7) * X_B;
    #pragma unroll
    for (int i = 0; i < 16; i++) {
        int e = t + 256 * i;
        int r = e >> 6, col = e & 63;
        L[r][col] = ip[(size_t)(c0 + r) * HWP + n0 + col];
    }
    __syncthreads();
    #pragma unroll
    for (int i = 0; i < 4; i++) {
        int e = t + 256 * i;
        int n = e >> 4, c4 = e & 15;
        ushort hi[4];
        #pragma unroll
        for (int j = 0; j < 4; j++)
            hi[j] = f2bf(L[c4 * 4 + j][n]);
        size_t base = ((size_t)z * HWP + n0 + n) * 192 + c0 + c4 * 4;
        *(ushort4*)&xt[base] = make_ushort4(hi[0], hi[1], hi[2], hi[3]);
    }
}

// ============================================================
// v bf16 (16 batch-slices,192,4096) -> VT (...,4096,192) transpose. z in [0,16).
// ============================================================
__global__ __launch_bounds__(256) void vtrans_kernel(const ushort* __restrict__ in,
    ushort* __restrict__ vt)
{
    __shared__ __align__(16) ushort L[64][72];
    const int n0 = blockIdx.x * 64, c0 = blockIdx.y * 64, z = blockIdx.z;
    const int t = threadIdx.x;
    const ushort* ip = in + (size_t)z * X_B;
    #pragma unroll
    for (int i = 0; i < 2; i++) {
        int e = t + 256 * i;            // 512 units of 8 ushorts
        int r = e >> 3, u8 = e & 7;
        *(bf16x8*)&L[r][u8 * 8] = *(const bf16x8*)&ip[(size_t)(c0 + r) * HWP + n0 + u8 * 8];
    }
    __syncthreads();
    #pragma unroll
    for (int i = 0; i < 4; i++) {
        int e = t + 256 * i;            // 1024: 64 n x 16 c4
        int n = e >> 4, c4 = e & 15;
        ushort o[4];
        #pragma unroll
        for (int j = 0; j < 4; j++) o[j] = L[c4 * 4 + j][n];
        *(ushort4*)&vt[((size_t)z * HWP + n0 + n) * 192 + c0 + c4 * 4] =
            make_ushort4(o[0], o[1], o[2], o[3]);
    }
}

// ============================================================
// w_qkv -> Wc(640,192) bf16 SINGLE, zero-padded rows 576..639
// ============================================================
__global__ __launch_bounds__(256) void wconvert_kernel(const float* __restrict__ wq,
    ushort* __restrict__ wc)
{
    int e = (blockIdx.x * 256 + threadIdx.x) * 4;    // 640*192 total
    int oc = e / 192, k = e % 192;
    ushort o[4] = {0, 0, 0, 0};
    if (oc < C3) {
        #pragma unroll
        for (int j = 0; j < 4; j++)
            o[j] = f2bf(wq[oc * CC + k + j]);
    }
    *(ushort4*)&wc[e] = make_ushort4(o[0], o[1], o[2], o[3]);
}

// ============================================================
// conv1x1 via MFMA, X-RESIDENT schedule (round-16 proven) + this round:
//  - E padded [128][136]: row stride 272B = 16 (mod 128B) -> kg row-groups
//    land on staggered bank sets -> <=2-way (free) for E writes AND reads
//  - ck=5 barrier dropped (epilogue's own syncthreads chain orders the
//    cross-mi W prefetch and protects Wsb WAR)
// ============================================================
__global__ __launch_bounds__(512) void conv1x1_mfma(const ushort* __restrict__ XT,
    const ushort* __restrict__ Wc, ushort* __restrict__ t1s)
{
    __shared__ __align__(16) ushort Xres[6][1024 * 8];  // 6 x 16 KB resident
    __shared__ __align__(16) ushort Wsb[2][512 * 8];    // 2 x 8 KB dbuf
    __shared__ __align__(16) ushort E[128][136];        // 34 KB epilogue (padded)
    const int t = threadIdx.x;
    const int lane = t & 63, w = t >> 6;
    const int wm = w >> 2, wn = w & 3;
    const int fr = lane & 15, kg = lane >> 4;
    const int g = blockIdx.x;
    const int bg = g & 7, s = g >> 3;           // s in [0,32)
    const int tsr = s >> 4;
    const int nt = s & 15;
    const int n0 = nt * 256;
    const ushort* XTp = XT + (size_t)(tsr * 8 + bg) * (HWP * 192);
    ushort* ob = t1s + (size_t)(tsr * 8 + bg) * QKV_B;

    // ---- stage all X chunks (linear dest per chunk, paired-row swizzle) ----
    #pragma unroll
    for (int ck = 0; ck < 6; ck++) {
        const int k0 = ck * 32;
        #pragma unroll
        for (int i = 0; i < 2; i++) {
            int u = i * 512 + t;                // 1024 units: 256 rows x 4 units
            int rp = u >> 3;
            int p = (u & 7) ^ (rp & 7);
            int r = (rp << 1) | (p >> 2);
            int c = p & 3;
            const ushort* gx = XTp + (size_t)(n0 + r) * 192 + k0 + c * 8;
            __builtin_amdgcn_global_load_lds(AS1(gx), AS3(&Xres[ck][(size_t)(i * 512 + t) * 8]), 16, 0, 0);
        }
    }

    auto STAGE_W = [&](int buf, int mi, int ck) {
        const int k0 = ck * 32;
        int u = t;                              // 512 units: 128 rows x 4 units
        int rp = u >> 3;
        int p = (u & 7) ^ (rp & 7);
        int r = (rp << 1) | (p >> 2);
        int c = p & 3;
        const ushort* gw = Wc + (size_t)(mi * 128 + r) * 192 + k0 + c * 8;
        __builtin_amdgcn_global_load_lds(AS1(gw), AS3(&Wsb[buf][(size_t)t * 8]), 16, 0, 0);
    };

    STAGE_W(0, 0, 0);
    __syncthreads();                 // X + W(0,0) resident
    int cur = 0;

    for (int mi = 0; mi < 5; mi++) {
        f32x4 acc[4][4] = {};
        for (int ck = 0; ck < 6; ck++) {
            if (mi * 6 + ck < 29) {
                int nmi = (ck == 5) ? mi + 1 : mi;
                int nck = (ck == 5) ? 0 : ck + 1;
                STAGE_W(cur ^ 1, nmi, nck);     // prefetch next W chunk
            }
            bf16x8 afh[4], bfr[4];
            #pragma unroll
            for (int m = 0; m < 4; m++) {
                int R = wm * 64 + m * 16 + fr;  // [0,128)
                int unit = (R >> 1) * 8 + ((((R & 1) << 2) | kg) ^ ((R >> 1) & 7));
                afh[m] = *(const bf16x8*)&Wsb[cur][unit * 8];
            }
            #pragma unroll
            for (int n = 0; n < 4; n++) {
                int R = wn * 64 + n * 16 + fr;  // [0,256)
                int unit = (R >> 1) * 8 + ((((R & 1) << 2) | kg) ^ ((R >> 1) & 7));
                bfr[n] = *(const bf16x8*)&Xres[ck][unit * 8];
            }
            #pragma unroll
            for (int m = 0; m < 4; m++)
                #pragma unroll
                for (int n = 0; n < 4; n++)
                    acc[m][n] = __builtin_amdgcn_mfma_f32_16x16x32_bf16(afh[m], bfr[n], acc[m][n], 0, 0, 0);
            if (ck < 5) __syncthreads();  // W prefetch done + WAR safe
            // (ck==5 barrier redundant: epilogue barriers drain + order)
            cur ^= 1;
        }

        // epilogue for this mi: two 128x128 half-tiles via E
        const int m0 = mi * 128;
        #pragma unroll
        for (int hf = 0; hf < 2; hf++) {
            if (hf) __syncthreads();
            if ((wn >> 1) == hf) {
                int wn2 = wn & 1;
                #pragma unroll
                for (int m = 0; m < 4; m++) {
                    int rl = wm * 64 + m * 16 + kg * 4;
                    #pragma unroll
                    for (int n = 0; n < 4; n++) {
                        int cl = wn2 * 64 + n * 16 + fr;
                        #pragma unroll
                        for (int r = 0; r < 4; r++)
                            E[rl + r][cl] = f2bf(acc[m][n][r]);
                    }
                }
            }
            __syncthreads();
            #pragma unroll
            for (int i = 0; i < 4; i++) {
                int u = t + 512 * i;            // 2048: 128 rows x 16 col-units
                int row = u >> 4, c8 = u & 15;
                int oc = m0 + row;
                if (oc < C3)
                    *(bf16x8*)&ob[(size_t)oc * HWP + n0 + hf * 128 + c8 * 8] =
                        *(bf16x8*)&E[row][c8 * 8];
            }
        }
        __syncthreads();             // E reads done before next mi overwrites
    }
}

// ============================================================
// depthwise 3x3, both tensors (grid 9216). 4x4 register-blocked rolling
// window (proven). q/k bf16 + fused L2 norm; v bf16.
// ============================================================
__global__ __launch_bounds__(256) void dw3x3_kernel(const ushort* __restrict__ inp,
    const float* __restrict__ wd,
    ushort* __restrict__ qh0, ushort* __restrict__ vv0, float* __restrict__ inv0)
{
    __shared__ float P[66][76];
    const int bcg = blockIdx.x;
    const int tsr = bcg / (BB * C3);
    const int bc = bcg - tsr * (BB * C3);       // b*576 + ch
    const int b = bc / C3, ch = bc % C3;
    const int t = threadIdx.x;
    const ushort* ip = inp + (size_t)tsr * ((size_t)BB * QKV_B) + (size_t)bc * HWP;
    ushort* qh = qh0 + (size_t)tsr * 12582912;
    ushort* vv = vv0 + (size_t)tsr * 6291456;
    float* inv = inv0 + (size_t)tsr * 3072;
    float wr[9];
    #pragma unroll
    for (int k = 0; k < 9; k++) wr[k] = wd[ch * 9 + k];
    for (int i = t; i < 66 * 76; i += 256) ((float*)P)[i] = 0.f;
    __syncthreads();
    #pragma unroll
    for (int i = 0; i < 2; i++) {
        int u = t + 256 * i;            // 512 units of 8 px
        int y = u >> 3, x0 = (u & 7) * 8;
        bf16x8 v8 = *(const bf16x8*)&ip[u * 8];
        float f0 = bf2f((ushort)v8[0]), f1 = bf2f((ushort)v8[1]);
        float f2 = bf2f((ushort)v8[2]), f3 = bf2f((ushort)v8[3]);
        float f4 = bf2f((ushort)v8[4]), f5 = bf2f((ushort)v8[5]);
        float f6 = bf2f((ushort)v8[6]), f7 = bf2f((ushort)v8[7]);
        *(float4*)&P[1 + y][4 + x0]     = make_float4(f0, f1, f2, f3);
        *(float4*)&P[1 + y][4 + x0 + 4] = make_float4(f4, f5, f6, f7);
    }
    __syncthreads();

    const int tx = t & 15, ty = t >> 4;
    const int x0 = tx * 4, y0 = ty * 4;

    float ssum = 0.f;
    float4 a0 = *(float4*)&P[y0][x0], b0 = *(float4*)&P[y0][x0 + 4], c0 = *(float4*)&P[y0][x0 + 8];
    float4 a1 = *(float4*)&P[y0 + 1][x0], b1 = *(float4*)&P[y0 + 1][x0 + 4], c1 = *(float4*)&P[y0 + 1][x0 + 8];
    #pragma unroll
    for (int r = 0; r < 4; r++) {
        float4 a2 = *(float4*)&P[y0 + r + 2][x0];
        float4 b2 = *(float4*)&P[y0 + r + 2][x0 + 4];
        float4 c2 = *(float4*)&P[y0 + r + 2][x0 + 8];
        float res[4] = {0.f, 0.f, 0.f, 0.f};
        {
            float e0 = a0.w, e1 = b0.x, e2 = b0.y, e3 = b0.z, e4 = b0.w, e5 = c0.x;
            res[0] += wr[0]*e0 + wr[1]*e1 + wr[2]*e2;
            res[1] += wr[0]*e1 + wr[1]*e2 + wr[2]*e3;
            res[2] += wr[0]*e2 + wr[1]*e3 + wr[2]*e4;
            res[3] += wr[0]*e3 + wr[1]*e4 + wr[2]*e5;
        }
        {
            float e0 = a1.w, e1 = b1.x, e2 = b1.y, e3 = b1.z, e4 = b1.w, e5 = c1.x;
            res[0] += wr[3]*e0 + wr[4]*e1 + wr[5]*e2;
            res[1] += wr[3]*e1 + wr[4]*e2 + wr[5]*e3;
            res[2] += wr[3]*e2 + wr[4]*e3 + wr[5]*e4;
            res[3] += wr[3]*e3 + wr[4]*e4 + wr[5]*e5;
        }
        {
            float e0 = a2.w, e1 = b2.x, e2 = b2.y, e3 = b2.z, e4 = b2.w, e5 = c2.x;
            res[0] += wr[6]*e0 + wr[7]*e1 + wr[8]*e2;
            res[1] += wr[6]*e1 + wr[7]*e2 + wr[8]*e3;
            res[2] += wr[6]*e2 + wr[7]*e3 + wr[8]*e4;
            res[3] += wr[6]*e3 + wr[7]*e4 + wr[8]*e5;
        }
        #pragma unroll
        for (int k = 0; k < 4; k++) ssum += res[k] * res[k];
        int px = (y0 + r) * WW + x0;
        if (ch < 384) {
            size_t base = ((size_t)b * 384 + ch) * HWP + px;
            *(ushort4*)&qh[base] = make_ushort4(f2bf(res[0]), f2bf(res[1]),
                                                f2bf(res[2]), f2bf(res[3]));
        } else {
            size_t base = ((size_t)b * CC + (ch - 384)) * HWP + px;
            *(ushort4*)&vv[base] = make_ushort4(f2bf(res[0]), f2bf(res[1]),
                                                f2bf(res[2]), f2bf(res[3]));
        }
        a0 = a1; b0 = b1; c0 = c1;
        a1 = a2; b1 = b2; c1 = c2;
    }
    if (ch < 384) {
        #pragma unroll
        for (int off = 32; off > 0; off >>= 1) ssum += __shfl_down(ssum, off);
        __shared__ float red[4];
        if ((t & 63) == 0) red[t >> 6] = ssum;
        __syncthreads();
        if (t == 0) {
            float tot = red[0] + red[1] + red[2] + red[3];
            inv[b * 384 + ch] = 1.f / fmaxf(sqrtf(tot), 1e-12f);
        }
    }
}

// ============================================================
// stacked Gram via MFMA, single bf16 (proven, unchanged)
// ============================================================
__global__ __launch_bounds__(256) void gram_mfma(const ushort* __restrict__ qhx,
    const ushort* __restrict__ qhy, float* __restrict__ spart)
{
    __shared__ __align__(16) ushort As[96 * 64];
    __shared__ __align__(16) ushort Bs[96 * 64];
    const int chunk = blockIdx.x, bh = blockIdx.y;
    const int b = bh >> 2, h = bh & 3;
    const int t = threadIdx.x;
    const int lane = t & 63, w = t >> 6;
    const int wm = w >> 1, wn = w & 1;
    const int fr = lane & 15, kg = lane >> 4;

    const size_t qbase = ((size_t)b * 384 + h * DH) * HWP;
    const size_t kbase = ((size_t)b * 384 + 192 + h * DH) * HWP;

    f32x4 acc[3][3] = {};

    for (int ks = 0; ks < 8; ks++) {
        const int n0 = chunk * 512 + ks * 64;
        #pragma unroll
        for (int i = 0; i < 3; i++) {
            int u = i * 256 + w * 64 + lane;
            int r = u >> 3, c = u & 7;
            int cs = c ^ (r & 7);
            const ushort* ga = ((r < DH) ? (qhx + qbase + (size_t)r * HWP)
                                         : (qhy + qbase + (size_t)(r - DH) * HWP))
                               + n0 + cs * 8;
            __builtin_amdgcn_global_load_lds(AS1(ga), AS3(&As[(size_t)(i * 4 + w) * 512]), 16, 0, 0);
            const ushort* gb = ((r < DH) ? (qhx + kbase + (size_t)r * HWP)
                                         : (qhy + kbase + (size_t)(r - DH) * HWP))
                               + n0 + cs * 8;
            __builtin_amdgcn_global_load_lds(AS1(gb), AS3(&Bs[(size_t)(i * 4 + w) * 512]), 16, 0, 0);
        }
        __syncthreads();
        #pragma unroll
        for (int kq = 0; kq < 8; kq += 4) {
            bf16x8 af[3], bfr[3];
            #pragma unroll
            for (int m = 0; m < 3; m++) {
                int R = wm * DH + m * 16 + fr;
                int unit = R * 8 + ((kq + kg) ^ (R & 7));
                af[m] = *(const bf16x8*)&As[unit * 8];
            }
            #pragma unroll
            for (int n = 0; n < 3; n++) {
                int R = wn * DH + n * 16 + fr;
                int unit = R * 8 + ((kq + kg) ^ (R & 7));
                bfr[n] = *(const bf16x8*)&Bs[unit * 8];
            }
            #pragma unroll
            for (int m = 0; m < 3; m++)
                #pragma unroll
                for (int n = 0; n < 3; n++)
                    acc[m][n] = __builtin_amdgcn_mfma_f32_16x16x32_bf16(af[m], bfr[n], acc[m][n], 0, 0, 0);
        }
        __syncthreads();
    }

    float* sp = spart + ((size_t)chunk * 32 + bh) * 9216;
    #pragma unroll
    for (int m = 0; m < 3; m++) {
        int row = wm * DH + m * 16 + kg * 4;
        #pragma unroll
        for (int n = 0; n < 3; n++) {
            int col = wn * DH + n * 16 + fr;
            #pragma unroll
            for (int r = 0; r < 4; r++)
                sp[(row + r) * 96 + col] = acc[m][n][r];
        }
    }
}

// ============================================================
// combine split-K partials, scale, softmax; emit single-bf16 coefficient
// matrix M'(96 x 128): two BK=64 chunks [Mx|My], cols 48..63 of each zeroed
// ============================================================
__global__ __launch_bounds__(256) void softmax_kernel(const float* __restrict__ spart,
    const float* __restrict__ invx, const float* __restrict__ invy,
    const float* __restrict__ temp, ushort* __restrict__ mpp)
{
    __shared__ float G[96][97];
    const int bh = blockIdx.x, b = bh >> 2, h = bh & 3;
    const int t = threadIdx.x;
    const float ts = temp[h];
    for (int i = 0; i < 36; i++) {
        int f = t + 256 * i;
        float s = 0.f;
        #pragma unroll
        for (int cch = 0; cch < 8; cch++)
            s += spart[((size_t)cch * 32 + bh) * 9216 + f];
        int r = f / 96, c = f % 96;
        float iq = (r < DH) ? invx[b*384 + h*DH + r] : invy[b*384 + h*DH + (r-DH)];
        float ik = (c < DH) ? invx[b*384 + CC + h*DH + c] : invy[b*384 + CC + h*DH + (c-DH)];
        G[r][c] = s * iq * ik * ts;
    }
    __syncthreads();
    if (t < 192) {
        int r = t >> 1, hf = t & 1;
        float* rowp = &G[r][hf * DH];
        float m = rowp[0];
        for (int i = 1; i < DH; i++) m = fmaxf(m, rowp[i]);
        float s = 0.f;
        for (int i = 0; i < DH; i++) { float e = __expf(rowp[i] - m); rowp[i] = e; s += e; }
        float inv = 1.f / s;
        for (int i = 0; i < DH; i++) rowp[i] *= inv;
    }
    __syncthreads();
    ushort* mo = mpp + (size_t)bh * 96 * 128;
    for (int i = 0; i < 12; i++) {
        int f = t + 256 * i;                 // 96 rows x 32 pad cols
        int r = f / 32, p = f % 32;
        int ch = p >> 4, j = p & 15;
        mo[(size_t)r * 128 + ch * 64 + 48 + j] = 0;
    }
    for (int i = 0; i < 36; i++) {
        int f = t + 256 * i;
        int r = f / 96, c = f % 96;
        float v;
        if (c < DH) v = (r < DH) ? G[DH + r][c] : G[r - DH][c];
        else        v = G[r][c];
        ushort hi = f2bf(v);
        if (c < DH) mo[(size_t)r * 128 + c] = hi;
        else        mo[(size_t)r * 128 + 64 + (c - DH)] = hi;
    }
}

// ============================================================
// output GEMM via MFMA (proven, unchanged)
// ============================================================
__global__ __launch_bounds__(256) void outmm_mfma(const ushort* __restrict__ VTx,
    const ushort* __restrict__ VTy, const ushort* __restrict__ mpp,
    float* __restrict__ out)
{
    __shared__ __align__(16) ushort As[96 * 64];
    __shared__ __align__(16) ushort Bs[128 * 64];
    const int t = threadIdx.x;
    const int lane = t & 63, w = t >> 6;
    const int wm = w >> 1, wn = w & 1;
    const int fr = lane & 15, kg = lane >> 4;
    const int nc = blockIdx.x, bh = blockIdx.y;
    const int b = bh >> 2, h = bh & 3;
    const int n0 = nc * 128;
    const ushort* mp = mpp + (size_t)bh * 96 * 128;

    f32x4 acc[3][4] = {};

    for (int kc = 0; kc < 2; kc++) {
        const ushort* Vsrc = kc ? VTy : VTx;
        const int coff = h * DH;
        const int aoff = kc * 64;
        #pragma unroll
        for (int i = 0; i < 3; i++) {
            int u = i * 256 + w * 64 + lane;
            int r = u >> 3, c = u & 7;
            int cs = c ^ (r & 7);
            const ushort* ga = mp + (size_t)r * 128 + aoff + cs * 8;
            __builtin_amdgcn_global_load_lds(AS1(ga), AS3(&As[(size_t)(i * 4 + w) * 512]), 16, 0, 0);
        }
        #pragma unroll
        for (int i = 0; i < 4; i++) {
            int u = i * 256 + w * 64 + lane;
            int r = u >> 3, c = u & 7;
            int cs = c ^ (r & 7);
            int c8 = coff + cs * 8;
            if (c8 >= 192) c8 -= 192;       // wrap: lands on zero-A K-rows
            const ushort* gb = Vsrc + ((size_t)(b * HWP + n0 + r)) * 192 + c8;
            __builtin_amdgcn_global_load_lds(AS1(gb), AS3(&Bs[(size_t)(i * 4 + w) * 512]), 16, 0, 0);
        }
        __syncthreads();
        #pragma unroll
        for (int kq = 0; kq < 8; kq += 4) {
            bf16x8 af[3], bfr[4];
            #pragma unroll
            for (int m = 0; m < 3; m++) {
                int R = wm * DH + m * 16 + fr;
                int unit = R * 8 + ((kq + kg) ^ (R & 7));
                af[m] = *(const bf16x8*)&As[unit * 8];
            }
            #pragma unroll
            for (int n = 0; n < 4; n++) {
                int R = wn * 64 + n * 16 + fr;
                int unit = R * 8 + ((kq + kg) ^ (R & 7));
                bfr[n] = *(const bf16x8*)&Bs[unit * 8];
            }
            #pragma unroll
            for (int m = 0; m < 3; m++)
                #pragma unroll
                for (int n = 0; n < 4; n++)
                    acc[m][n] = __builtin_amdgcn_mfma_f32_16x16x32_bf16(af[m], bfr[n], acc[m][n], 0, 0, 0);
        }
        __syncthreads();
    }

    #pragma unroll
    for (int m = 0; m < 3; m++) {
        int row = wm * DH + m * 16 + kg * 4;
        #pragma unroll
        for (int n = 0; n < 4; n++) {
            int col = n0 + wn * 64 + n * 16 + fr;
            #pragma unroll
            for (int r = 0; r < 4; r++) {
                int rr = row + r;
                float* dst = (rr < DH)
                    ? (out + (size_t)b * X_B + (h * DH + rr) * HWP + col)
                    : (out + OUT_HALF + (size_t)b * X_B + (h * DH + rr - DH) * HWP + col);
                *dst = acc[m][n][r];
            }
        }
    }
}

// ============================================================
extern "C" void kernel_launch(void* const* d_in, const int* in_sizes, int n_in,
                              void* d_out, int out_size, void* d_ws, size_t ws_size,
                              hipStream_t stream)
{
    const float* x  = (const float*)d_in[0];
    const float* y  = (const float*)d_in[1];
    const float* wq = (const float*)d_in[2];
    const float* wd = (const float*)d_in[3];
    const float* tp = (const float*)d_in[4];
    float* out = (float*)d_out;
    float* ws = (float*)d_ws;

    // ---- workspace layout (float units), total ~176 MB of 256 MB ----
    ushort* qh0 = (ushort*)ws;
    float*  v0f = ws + 12582912;
    ushort* v0  = (ushort*)v0f;
    float*  t10 = ws + 12582912 + 6291456;
    ushort* t1s = (ushort*)t10;
    ushort* XT  = (ushort*)(ws + 12582912 + 6291456 + 18874368);
    ushort* Wc  = (ushort*)(ws + 12582912 + 6291456 + 18874368 + 6291456);
    float*  inv0 = ws + 12582912 + 6291456 + 18874368 + 6291456 + 61440;
    float*  invx = inv0;
    float*  invy = inv0 + 3072;
    // aliases over t1 region (dead after dw):
    ushort* VTx  = t1s;
    ushort* VTy  = (ushort*)(t10 + 3145728);
    float*  spart = t10 + 6291456;
    ushort* Mpp  = (ushort*)(t10 + 6291456 + 2359296);
    ushort* qhx = qh0;
    ushort* qhy = qh0 + 12582912;

    wconvert_kernel<<<120, 256, 0, stream>>>(wq, Wc);

    // both tensors: convert -> conv -> dw (one dispatch each)
    convert_single_kernel<<<dim3(64, 3, 16), 256, 0, stream>>>(x, y, XT);
    conv1x1_mfma<<<256, 512, 0, stream>>>(XT, Wc, t1s);
    dw3x3_kernel<<<2 * BB * C3, 256, 0, stream>>>(t1s, wd, qh0, v0, inv0);

    // transpose v (both tensors) into dead t1 region
    vtrans_kernel<<<dim3(64, 3, 16), 256, 0, stream>>>(v0, VTx);

    gram_mfma<<<dim3(8, 32), 256, 0, stream>>>(qhx, qhy, spart);
    softmax_kernel<<<32, 256, 0, stream>>>(spart, invx, invy, tp, Mpp);
    outmm_mfma<<<dim3(HWP / 128, 32), 256, 0, stream>>>(VTx, VTy, Mpp, out);
}